// Round 6
// baseline (131.300 us; speedup 1.0000x reference)
//
#include <hip/hip_runtime.h>
#include <hip/hip_fp16.h>
#include <math.h>

#define Bn 16
#define Tn 2048
#define Fn 1025
#define KP 1056       // padded K = 33 * 32 (basisT row stride)
#define KROW 1064     // LDS u row stride in fp16 (2128 B -> 20 mod 32 banks/row)
#define ROWS 8        // rows per block -> 17 KB LDS -> 8 blocks/CU
#define Dn 64
#define EPSF 1e-6f

typedef __attribute__((ext_vector_type(8))) _Float16 f16x8;
typedef __attribute__((ext_vector_type(4))) _Float16 f16x4;
typedef __attribute__((ext_vector_type(4))) float f32x4;

__device__ inline float waveReduceSum(float v) {
#pragma unroll
  for (int off = 32; off > 0; off >>= 1) v += __shfl_xor(v, off, 64);
  return v;
}

// ---------------- prep: basisT[d][k] fp16 (normalized), spacing outputs ----------------
__global__ __launch_bounds__(256) void prep_kernel(
    const float* __restrict__ freq, const float* __restrict__ spacing,
    _Float16* __restrict__ basisT, float* __restrict__ out2, float* __restrict__ out3) {
  __shared__ float wsum[4];
  const int d = blockIdx.x;
  const int tid = threadIdx.x;
  const float sp = fmaxf(spacing[d], 1e-6f);

  float pv[5];
  float lsum = 0.f;
#pragma unroll
  for (int it = 0; it < 5; ++it) {
    int f = tid + 256 * it;
    float p = 0.f;
    if (f < Fn) {
      double arg = 6.2831853071795864769 * (double)(freq[f] / sp);
      p = 0.5f * (1.0f + (float)cos(arg));
      lsum += p;
    }
    pv[it] = p;
  }
  float s = waveReduceSum(lsum);
  if ((tid & 63) == 0) wsum[tid >> 6] = s;
  __syncthreads();
  float inv = 1.0f / fmaxf((wsum[0] + wsum[1] + wsum[2] + wsum[3]) * (1.0f / 1025.0f), EPSF);

#pragma unroll
  for (int it = 0; it < 5; ++it) {
    int f = tid + 256 * it;
    if (f < KP) basisT[(size_t)d * KP + f] = (_Float16)(pv[it] * inv);
  }
  if (tid == 0) {
    out2[d] = spacing[d];
    out3[d] = 17150.0f / sp;
  }
}

// ---------------- fused: trough -> LDS -> MFMA -> epilogue ----------------
__global__ __launch_bounds__(256) void fused_kernel(
    const float* __restrict__ phase, const float* __restrict__ comb,
    const _Float16* __restrict__ basisT,
    const float* __restrict__ scalar, const float* __restrict__ obs_m,
    const float* __restrict__ rel_m, const float* __restrict__ stpacc,
    float* __restrict__ out0, float* __restrict__ out1) {
  __shared__ _Float16 uLDS[ROWS * KROW];   // 17024 B; reused as cum[8][5][65] f32
  __shared__ float rowScale[ROWS];

  const int lane = threadIdx.x & 63;
  const int w = __builtin_amdgcn_readfirstlane(threadIdx.x >> 6);
  const int row0 = blockIdx.x * ROWS;

  // ---- Phase 1: trough for rows 2w, 2w+1; UNSCALED u (fp16) -> LDS ----
#pragma unroll 1
  for (int k4 = 0; k4 < 2; ++k4) {
    const int rl = w * 2 + k4;
    const int row = row0 + rl;
    const int b = row >> 11;
    const int t = row & 2047;

    const float* prow  = phase + (size_t)row * Fn;
    const float* c0row = comb + ((size_t)(b * 2 + 0) * Tn + t) * Fn;
    const float* c1row = comb + ((size_t)(b * 2 + 1) * Tn + t) * Fn;

    float4 pv[5], c0v[5], c1v[5];
#pragma unroll
    for (int it = 0; it < 5; ++it) {
      const int i = lane + 64 * it;
      if (i < 256) {
        pv[it]  = *(const float4*)(prow  + 4 * i);
        c0v[it] = *(const float4*)(c0row + 4 * i);
        c1v[it] = *(const float4*)(c1row + 4 * i);
      } else if (i == 256) {
        pv[it]  = make_float4(prow[1024],  0.f, 0.f, 0.f);
        c0v[it] = make_float4(c0row[1024], 0.f, 0.f, 0.f);
        c1v[it] = make_float4(c1row[1024], 0.f, 0.f, 0.f);
      } else {
        pv[it]  = make_float4(0.f, 0.f, 0.f, 0.f);
        c0v[it] = make_float4(0.f, 0.f, 0.f, 0.f);
        c1v[it] = make_float4(0.f, 0.f, 0.f, 0.f);
      }
    }

    float s = 0.f;
#pragma unroll
    for (int it = 0; it < 5; ++it)
      s += pv[it].x + pv[it].y + pv[it].z + pv[it].w;
    s = waveReduceSum(s);
    const float mean_lm = s * (1.0f / 1025.0f);

    _Float16* urow = uLDS + (size_t)rl * KROW;
    float su = 0.f;
#pragma unroll
    for (int it = 0; it < 5; ++it) {
      const int i = lane + 64 * it;
      float4 u;
      const float* pf = (const float*)&pv[it];
      const float* q0 = (const float*)&c0v[it];
      const float* q1 = (const float*)&c1v[it];
      float* uf = (float*)&u;
#pragma unroll
      for (int c2 = 0; c2 < 4; ++c2) {
        float tr = fmaxf(mean_lm - pf[c2], 0.f);
        float d1 = fabsf(q1[c2]) + 0.25f * fabsf(q0[c2]);
        uf[c2] = tr * (1.f + d1);
      }
      if (i > 256) { u.x = 0.f; u.y = 0.f; u.z = 0.f; u.w = 0.f; }
      else if (i == 256) { u.y = 0.f; u.z = 0.f; u.w = 0.f; }
      su += u.x + u.y + u.z + u.w;
      if (i < 264) {                       // k < 1056 (quads 257..263 store zeros)
        f16x4 hv;
#pragma unroll
        for (int c2 = 0; c2 < 4; ++c2) hv[c2] = (_Float16)uf[c2];
        *(f16x4*)(urow + 4 * i) = hv;
      }
    }
    su = waveReduceSum(su);
    if (lane == 0) rowScale[rl] = 1.0f / fmaxf(su * (1.0f / 1025.0f), EPSF);
  }
  __syncthreads();

  // ---- Phase 2: MFMA. wave = (khalf = w>>1, nhalf = w&1); 8 real rows, dup trick ----
  const int m16 = lane & 15;
  const int kg = lane >> 4;
  const int nh = w & 1;
  const int kh = w >> 1;
  const int d0 = nh * 32 + m16;

  const _Float16* ALp = uLDS + (size_t)(m16 & 7) * KROW + kg * 8;  // rows 8..15 dup 0..7
  const _Float16* B0 = basisT + (size_t)d0 * KP + kg * 8;
  const _Float16* B1 = basisT + (size_t)(d0 + 16) * KP + kg * 8;

  f32x4 acc0 = {0.f, 0.f, 0.f, 0.f};
  f32x4 acc1 = {0.f, 0.f, 0.f, 0.f};
  f32x4 s0a = acc0, s0b = acc0, s1a = acc0, s1b = acc0, s2a = acc0, s2b = acc0;

  auto loadA = [&](int kt) { return *(const f16x8*)(ALp + kt * 32); };
  auto tileA = [&](int kt, f16x8 a) {
    f16x8 b0 = *(const f16x8*)(B0 + kt * 32);
    f16x8 b1 = *(const f16x8*)(B1 + kt * 32);
    acc0 = __builtin_amdgcn_mfma_f32_16x16x32_f16(a, b0, acc0, 0, 0, 0);
    acc1 = __builtin_amdgcn_mfma_f32_16x16x32_f16(a, b1, acc1, 0, 0, 0);
  };
  auto boundary = [&](int kt, int KB, f32x4& sa, f32x4& sb) {
    f16x8 a = loadA(kt);
    const int kb = kt * 32 + kg * 8;
    f16x8 alo, ahi;
#pragma unroll
    for (int j = 0; j < 8; ++j) {
      bool lo = (kb + j) < KB;
      alo[j] = lo ? a[j] : (_Float16)0.f;
      ahi[j] = lo ? (_Float16)0.f : a[j];
    }
    tileA(kt, alo);
    sa = acc0; sb = acc1;
    tileA(kt, ahi);
  };

  if (kh == 0) {
    boundary(0, 22, s0a, s0b);               // band0 ends k=22
    tileA(1, loadA(1));
    boundary(2, 86, s1a, s1b);               // band1 ends k=86
#pragma unroll
    for (int kt = 3; kt < 10; ++kt) tileA(kt, loadA(kt));
    boundary(10, 342, s2a, s2b);             // band2 ends k=342
#pragma unroll
    for (int kt = 11; kt < 16; ++kt) tileA(kt, loadA(kt));
  } else {
#pragma unroll
    for (int kt = 16; kt < 33; ++kt) tileA(kt, loadA(kt));
  }
  __syncthreads();   // u reads done; reuse LDS as cum[8][5][65] f32

  float* cumL = (float*)uLDS;
  auto stor = [&](int slot, const f32x4& v0, const f32x4& v1) {
    if (kg < 2) {                             // C rows 0..7 only (8..15 are dups)
#pragma unroll
      for (int r = 0; r < 4; ++r) {
        const int rr = kg * 4 + r;
        cumL[(rr * 5 + slot) * 65 + d0]      = v0[r];
        cumL[(rr * 5 + slot) * 65 + d0 + 16] = v1[r];
      }
    }
  };
  if (kh == 0) {
    stor(0, s0a, s0b);
    stor(1, s1a, s1b);
    stor(2, s2a, s2b);
    stor(3, acc0, acc1);   // cumulative over k-tiles 0..15
  } else {
    stor(4, acc0, acc1);   // sum over k-tiles 16..32
  }
  __syncthreads();

  // ---- Phase 3: epilogue. wave w -> rows 2w, 2w+1; lane = d ----
#pragma unroll
  for (int k4 = 0; k4 < 2; ++k4) {
    const int rl = w * 2 + k4;
    const size_t bt = (size_t)(row0 + rl);
    const float rs = rowScale[rl];

    float q0 = cumL[(rl * 5 + 0) * 65 + lane];
    float q1 = cumL[(rl * 5 + 1) * 65 + lane];
    float q2 = cumL[(rl * 5 + 2) * 65 + lane];
    float q3 = cumL[(rl * 5 + 3) * 65 + lane] + cumL[(rl * 5 + 4) * 65 + lane];
    float b0 = q0, b1 = q1 - q0, b2 = q2 - q1, b3 = q3 - q2;

    float sv = fmaxf(stpacc[bt * Dn + lane], 0.f);
    float ssum = waveReduceSum(sv);
    float stp = sv / fmaxf(ssum * (1.0f / 64.0f), EPSF);

    float4 scv = *(const float4*)(scalar + bt * 4);
    float4 om  = *(const float4*)(obs_m  + bt * 4);
    float4 rm  = *(const float4*)(rel_m  + bt * 4);
    float obs_q = (om.x + om.y + om.z + om.w) * 0.25f;
    float rel_q = (rm.x + rm.y + rm.z + rm.w) * 0.25f;
    float is_snd = fminf(fmaxf(scv.x, 0.f), 1.f);
    float rho = fabsf(fminf(fmaxf(scv.y, -1.f), 1.f));

    float c0 = q3 * rs * (1.0f / 1025.0f);
    float c1 = b0 * rs * (1.0f / 22.0f);
    float c2 = b1 * rs * (1.0f / 64.0f);
    float c3 = b2 * rs * (1.0f / 256.0f);
    float c4 = b3 * rs * (1.0f / 683.0f);

    float mean10 = (c0 + c1 + c2 + c3 + c4 + stp + obs_q + rel_q + is_snd + rho) * 0.1f;
    float logit = mean10 * (0.5f + 0.5f * is_snd);

    float2* op = (float2*)(out0 + (bt * Dn + lane) * 10);
    op[0] = make_float2(c0, c1);
    op[1] = make_float2(c2, c3);
    op[2] = make_float2(c4, stp);
    op[3] = make_float2(obs_q, rel_q);
    op[4] = make_float2(is_snd, rho);
    out1[bt * Dn + lane] = logit;
  }
}

extern "C" void kernel_launch(void* const* d_in, const int* in_sizes, int n_in,
                              void* d_out, int out_size, void* d_ws, size_t ws_size,
                              hipStream_t stream) {
  const float* phase   = (const float*)d_in[0];
  const float* comb    = (const float*)d_in[1];
  const float* scalar  = (const float*)d_in[2];
  const float* obs_m   = (const float*)d_in[3];
  const float* rel_m   = (const float*)d_in[4];
  const float* stpacc  = (const float*)d_in[5];
  const float* freq    = (const float*)d_in[6];
  const float* spacing = (const float*)d_in[7];

  float* out  = (float*)d_out;
  float* out0 = out;                                    // (B,T,D,10)
  float* out1 = out + (size_t)Bn * Tn * Dn * 10;        // (B,T,D)
  float* out2 = out1 + (size_t)Bn * Tn * Dn;            // (D,)
  float* out3 = out2 + Dn;                              // (D,)

  _Float16* basisT = (_Float16*)d_ws;                   // 64*KP fp16 = 135 KB

  prep_kernel<<<Dn, 256, 0, stream>>>(freq, spacing, basisT, out2, out3);
  fused_kernel<<<Bn * Tn / ROWS, 256, 0, stream>>>(
      phase, comb, basisT, scalar, obs_m, rel_m, stpacc, out0, out1);
}

// Round 7
// 124.015 us; speedup vs baseline: 1.0587x; 1.0587x over previous
//
#include <hip/hip_runtime.h>
#include <hip/hip_fp16.h>
#include <math.h>

#define Bn 16
#define Tn 2048
#define Fn 1025
#define KP 1056       // padded K = 33 * 32 (basisT row stride)
#define KROW 1064     // LDS u row stride in fp16 (2128 B -> 20 mod 32 banks/row, 2-way = free)
#define ROWS 16       // rows per block (16-row MFMA tile, no dup waste)
#define Dn 64
#define EPSF 1e-6f

typedef __attribute__((ext_vector_type(8))) _Float16 f16x8;
typedef __attribute__((ext_vector_type(4))) _Float16 f16x4;
typedef __attribute__((ext_vector_type(4))) float f32x4;

__device__ inline float waveReduceSum(float v) {
#pragma unroll
  for (int off = 32; off > 0; off >>= 1) v += __shfl_xor(v, off, 64);
  return v;
}
__device__ inline void waveReduceSum2(float& a, float& b) {
#pragma unroll
  for (int off = 32; off > 0; off >>= 1) {
    a += __shfl_xor(a, off, 64);
    b += __shfl_xor(b, off, 64);
  }
}

// ---------------- prep: basisT[d][k] fp16 (normalized), spacing outputs ----------------
__global__ __launch_bounds__(256) void prep_kernel(
    const float* __restrict__ freq, const float* __restrict__ spacing,
    _Float16* __restrict__ basisT, float* __restrict__ out2, float* __restrict__ out3) {
  __shared__ float wsum[4];
  const int d = blockIdx.x;
  const int tid = threadIdx.x;
  const float sp = fmaxf(spacing[d], 1e-6f);

  float pv[5];
  float lsum = 0.f;
#pragma unroll
  for (int it = 0; it < 5; ++it) {
    int f = tid + 256 * it;
    float p = 0.f;
    if (f < Fn) {
      double arg = 6.2831853071795864769 * (double)(freq[f] / sp);
      p = 0.5f * (1.0f + (float)cos(arg));
      lsum += p;
    }
    pv[it] = p;
  }
  float s = waveReduceSum(lsum);
  if ((tid & 63) == 0) wsum[tid >> 6] = s;
  __syncthreads();
  float inv = 1.0f / fmaxf((wsum[0] + wsum[1] + wsum[2] + wsum[3]) * (1.0f / 1025.0f), EPSF);

#pragma unroll
  for (int it = 0; it < 5; ++it) {
    int f = tid + 256 * it;
    if (f < KP) basisT[(size_t)d * KP + f] = (_Float16)(pv[it] * inv);
  }
  if (tid == 0) {
    out2[d] = spacing[d];
    out3[d] = 17150.0f / sp;
  }
}

// ---------------- fused: trough -> LDS -> MFMA -> epilogue ----------------
__global__ __launch_bounds__(256, 3) void fused_kernel(
    const float* __restrict__ phase, const float* __restrict__ comb,
    const _Float16* __restrict__ basisT,
    const float* __restrict__ scalar, const float* __restrict__ obs_m,
    const float* __restrict__ rel_m, const float* __restrict__ stpacc,
    float* __restrict__ out0, float* __restrict__ out1) {
  __shared__ _Float16 uLDS[ROWS * KROW];   // 34048 B; reused as cum[16][5][65] f32 (20.8 KB)
  __shared__ float rowScale[ROWS];

  const int lane = threadIdx.x & 63;
  const int w = __builtin_amdgcn_readfirstlane(threadIdx.x >> 6);
  const int row0 = blockIdx.x * ROWS;

  // ---- Phase 1: trough, 2 rows at a time with all loads in flight ----
  auto loadRow = [&](int row, float4* pv, float4* c0v, float4* c1v) {
    const int b = row >> 11;
    const int t = row & 2047;
    const float* prow  = phase + (size_t)row * Fn;
    const float* c0row = comb + ((size_t)(b * 2 + 0) * Tn + t) * Fn;
    const float* c1row = comb + ((size_t)(b * 2 + 1) * Tn + t) * Fn;
#pragma unroll
    for (int it = 0; it < 5; ++it) {
      const int i = lane + 64 * it;
      if (i < 256) {
        pv[it]  = *(const float4*)(prow  + 4 * i);
        c0v[it] = *(const float4*)(c0row + 4 * i);
        c1v[it] = *(const float4*)(c1row + 4 * i);
      } else if (i == 256) {
        pv[it]  = make_float4(prow[1024],  0.f, 0.f, 0.f);
        c0v[it] = make_float4(c0row[1024], 0.f, 0.f, 0.f);
        c1v[it] = make_float4(c1row[1024], 0.f, 0.f, 0.f);
      } else {
        pv[it]  = make_float4(0.f, 0.f, 0.f, 0.f);
        c0v[it] = make_float4(0.f, 0.f, 0.f, 0.f);
        c1v[it] = make_float4(0.f, 0.f, 0.f, 0.f);
      }
    }
  };
  auto rowSum = [&](const float4* pv) {
    float s = 0.f;
#pragma unroll
    for (int it = 0; it < 5; ++it)
      s += pv[it].x + pv[it].y + pv[it].z + pv[it].w;
    return s;
  };
  auto rowU = [&](int rl, float mean_lm, const float4* pv, const float4* c0v,
                  const float4* c1v) {
    _Float16* urow = uLDS + (size_t)rl * KROW;
    float su = 0.f;
#pragma unroll
    for (int it = 0; it < 5; ++it) {
      const int i = lane + 64 * it;
      float4 u;
      const float* pf = (const float*)&pv[it];
      const float* q0 = (const float*)&c0v[it];
      const float* q1 = (const float*)&c1v[it];
      float* uf = (float*)&u;
#pragma unroll
      for (int c2 = 0; c2 < 4; ++c2) {
        float tr = fmaxf(mean_lm - pf[c2], 0.f);
        float d1 = fabsf(q1[c2]) + 0.25f * fabsf(q0[c2]);
        uf[c2] = tr * (1.f + d1);
      }
      if (i > 256) { u.x = 0.f; u.y = 0.f; u.z = 0.f; u.w = 0.f; }
      else if (i == 256) { u.y = 0.f; u.z = 0.f; u.w = 0.f; }
      su += u.x + u.y + u.z + u.w;
      if (i < 264) {                       // quads 257..263 store zeros (k tail)
        f16x4 hv;
#pragma unroll
        for (int c2 = 0; c2 < 4; ++c2) hv[c2] = (_Float16)uf[c2];
        *(f16x4*)(urow + 4 * i) = hv;
      }
    }
    return su;
  };

#pragma unroll 1
  for (int p = 0; p < 2; ++p) {
    const int rA = w * 4 + p * 2;
    const int rB = rA + 1;
    float4 pvA[5], c0A[5], c1A[5], pvB[5], c0B[5], c1B[5];
    loadRow(row0 + rA, pvA, c0A, c1A);
    loadRow(row0 + rB, pvB, c0B, c1B);
    float sA = rowSum(pvA), sB = rowSum(pvB);
    waveReduceSum2(sA, sB);
    float suA = rowU(rA, sA * (1.0f / 1025.0f), pvA, c0A, c1A);
    float suB = rowU(rB, sB * (1.0f / 1025.0f), pvB, c0B, c1B);
    waveReduceSum2(suA, suB);
    if (lane == 0) {
      rowScale[rA] = 1.0f / fmaxf(suA * (1.0f / 1025.0f), EPSF);
      rowScale[rB] = 1.0f / fmaxf(suB * (1.0f / 1025.0f), EPSF);
    }
  }
  __syncthreads();

  // ---- Phase 2: MFMA. wave = (khalf = w>>1, nhalf = w&1); 16 real rows ----
  const int m16 = lane & 15;
  const int kg = lane >> 4;
  const int nh = w & 1;
  const int kh = w >> 1;
  const int d0 = nh * 32 + m16;

  const _Float16* ALp = uLDS + (size_t)m16 * KROW + kg * 8;
  const _Float16* B0 = basisT + (size_t)d0 * KP + kg * 8;
  const _Float16* B1 = basisT + (size_t)(d0 + 16) * KP + kg * 8;

  f32x4 acc0 = {0.f, 0.f, 0.f, 0.f};
  f32x4 acc1 = {0.f, 0.f, 0.f, 0.f};
  f32x4 s0a = acc0, s0b = acc0, s1a = acc0, s1b = acc0, s2a = acc0, s2b = acc0;

  auto loadA = [&](int kt) { return *(const f16x8*)(ALp + kt * 32); };
  auto tileA = [&](int kt, f16x8 a) {
    f16x8 b0 = *(const f16x8*)(B0 + kt * 32);
    f16x8 b1 = *(const f16x8*)(B1 + kt * 32);
    acc0 = __builtin_amdgcn_mfma_f32_16x16x32_f16(a, b0, acc0, 0, 0, 0);
    acc1 = __builtin_amdgcn_mfma_f32_16x16x32_f16(a, b1, acc1, 0, 0, 0);
  };
  auto boundary = [&](int kt, int KB, f32x4& sa, f32x4& sb) {
    f16x8 a = loadA(kt);
    const int kb = kt * 32 + kg * 8;
    f16x8 alo, ahi;
#pragma unroll
    for (int j = 0; j < 8; ++j) {
      bool lo = (kb + j) < KB;
      alo[j] = lo ? a[j] : (_Float16)0.f;
      ahi[j] = lo ? (_Float16)0.f : a[j];
    }
    tileA(kt, alo);
    sa = acc0; sb = acc1;
    tileA(kt, ahi);
  };

  if (kh == 0) {
    boundary(0, 22, s0a, s0b);               // band0 ends k=22
    tileA(1, loadA(1));
    boundary(2, 86, s1a, s1b);               // band1 ends k=86
#pragma unroll
    for (int kt = 3; kt < 10; ++kt) tileA(kt, loadA(kt));
    boundary(10, 342, s2a, s2b);             // band2 ends k=342
#pragma unroll
    for (int kt = 11; kt < 16; ++kt) tileA(kt, loadA(kt));
  } else {
#pragma unroll
    for (int kt = 16; kt < 33; ++kt) tileA(kt, loadA(kt));
  }
  __syncthreads();   // u reads done; reuse LDS as cum[16][5][65] f32

  float* cumL = (float*)uLDS;
  auto stor = [&](int slot, const f32x4& v0, const f32x4& v1) {
#pragma unroll
    for (int r = 0; r < 4; ++r) {
      const int rr = kg * 4 + r;
      cumL[(rr * 5 + slot) * 65 + d0]      = v0[r];
      cumL[(rr * 5 + slot) * 65 + d0 + 16] = v1[r];
    }
  };
  if (kh == 0) {
    stor(0, s0a, s0b);
    stor(1, s1a, s1b);
    stor(2, s2a, s2b);
    stor(3, acc0, acc1);   // cumulative over k-tiles 0..15
  } else {
    stor(4, acc0, acc1);   // sum over k-tiles 16..32
  }
  __syncthreads();

  // ---- Phase 3: epilogue. wave w -> rows 4w..4w+3; lane = d ----
#pragma unroll
  for (int k4 = 0; k4 < 4; ++k4) {
    const int rl = w * 4 + k4;
    const size_t bt = (size_t)(row0 + rl);
    const float rs = rowScale[rl];

    float sv = fmaxf(stpacc[bt * Dn + lane], 0.f);

    float q0 = cumL[(rl * 5 + 0) * 65 + lane];
    float q1 = cumL[(rl * 5 + 1) * 65 + lane];
    float q2 = cumL[(rl * 5 + 2) * 65 + lane];
    float q3 = cumL[(rl * 5 + 3) * 65 + lane] + cumL[(rl * 5 + 4) * 65 + lane];
    float b0 = q0, b1 = q1 - q0, b2 = q2 - q1, b3 = q3 - q2;

    float ssum = waveReduceSum(sv);
    float stp = sv / fmaxf(ssum * (1.0f / 64.0f), EPSF);

    float4 scv = *(const float4*)(scalar + bt * 4);
    float4 om  = *(const float4*)(obs_m  + bt * 4);
    float4 rm  = *(const float4*)(rel_m  + bt * 4);
    float obs_q = (om.x + om.y + om.z + om.w) * 0.25f;
    float rel_q = (rm.x + rm.y + rm.z + rm.w) * 0.25f;
    float is_snd = fminf(fmaxf(scv.x, 0.f), 1.f);
    float rho = fabsf(fminf(fmaxf(scv.y, -1.f), 1.f));

    float c0 = q3 * rs * (1.0f / 1025.0f);
    float c1 = b0 * rs * (1.0f / 22.0f);
    float c2 = b1 * rs * (1.0f / 64.0f);
    float c3 = b2 * rs * (1.0f / 256.0f);
    float c4 = b3 * rs * (1.0f / 683.0f);

    float mean10 = (c0 + c1 + c2 + c3 + c4 + stp + obs_q + rel_q + is_snd + rho) * 0.1f;
    float logit = mean10 * (0.5f + 0.5f * is_snd);

    float2* op = (float2*)(out0 + (bt * Dn + lane) * 10);
    op[0] = make_float2(c0, c1);
    op[1] = make_float2(c2, c3);
    op[2] = make_float2(c4, stp);
    op[3] = make_float2(obs_q, rel_q);
    op[4] = make_float2(is_snd, rho);
    out1[bt * Dn + lane] = logit;
  }
}

extern "C" void kernel_launch(void* const* d_in, const int* in_sizes, int n_in,
                              void* d_out, int out_size, void* d_ws, size_t ws_size,
                              hipStream_t stream) {
  const float* phase   = (const float*)d_in[0];
  const float* comb    = (const float*)d_in[1];
  const float* scalar  = (const float*)d_in[2];
  const float* obs_m   = (const float*)d_in[3];
  const float* rel_m   = (const float*)d_in[4];
  const float* stpacc  = (const float*)d_in[5];
  const float* freq    = (const float*)d_in[6];
  const float* spacing = (const float*)d_in[7];

  float* out  = (float*)d_out;
  float* out0 = out;                                    // (B,T,D,10)
  float* out1 = out + (size_t)Bn * Tn * Dn * 10;        // (B,T,D)
  float* out2 = out1 + (size_t)Bn * Tn * Dn;            // (D,)
  float* out3 = out2 + Dn;                              // (D,)

  _Float16* basisT = (_Float16*)d_ws;                   // 64*KP fp16 = 135 KB

  prep_kernel<<<Dn, 256, 0, stream>>>(freq, spacing, basisT, out2, out3);
  fused_kernel<<<Bn * Tn / ROWS, 256, 0, stream>>>(
      phase, comb, basisT, scalar, obs_m, rel_m, stpacc, out0, out1);
}